// Round 3
// baseline (398.657 us; speedup 1.0000x reference)
//
#include <hip/hip_runtime.h>
#include <hip/hip_bf16.h>

#define NN 8192
#define FIN 128
#define FOUT 64
#define ALPHA 0.2f
#define CHUNK 256            // j-tile per iteration
#define BM 16                // rows per attn block
#define SPLIT 4              // j-range split factor (2048 j per block)
#define JSLICE (NN / SPLIT)
#define NCHUNK (JSLICE / CHUNK)
#define PROW (CHUNK + 8)     // +16B pad: breaks 512B stride, keeps 16B align

typedef __attribute__((ext_vector_type(8))) short short8;   // 8 bf16 (4 VGPRs)
typedef __attribute__((ext_vector_type(4))) float floatx4;

static __device__ __forceinline__ ushort f2bf(float f) {
    __hip_bfloat16 h = __float2bfloat16(f);
    return __builtin_bit_cast(ushort, h);
}

// K1: WhT[f][row] = bf16(x @ W); Wh1 = Wh@a[:64]; Wh2 = Wh@a[64:]  (fp32)
// grid NN/32 x 256: wave handles 8 rows sequentially; LDS transpose -> coalesced WhT.
__global__ __launch_bounds__(256) void gat_proj(const float* __restrict__ x,
                                                const float* __restrict__ W,
                                                const float* __restrict__ a,
                                                ushort* __restrict__ WhT,
                                                float* __restrict__ Wh1,
                                                float* __restrict__ Wh2) {
    __shared__ float tile[32][FOUT + 1];   // +1: transpose reads conflict-free

    const int t = threadIdx.x;
    const int f = t & 63;
    const int wv = t >> 6;
    const int row0 = blockIdx.x * 32;
    const float af1 = a[f], af2 = a[FOUT + f];

    for (int r8 = 0; r8 < 8; ++r8) {
        const int row = row0 + wv * 8 + r8;
        const float4* __restrict__ x4 = (const float4*)(x + (size_t)row * FIN);
        float acc = 0.f;
        #pragma unroll
        for (int k4 = 0; k4 < FIN / 4; ++k4) {
            float4 xv = x4[k4];
            const int k = k4 * 4;
            acc = fmaf(xv.x, W[(k + 0) * FOUT + f], acc);
            acc = fmaf(xv.y, W[(k + 1) * FOUT + f], acc);
            acc = fmaf(xv.z, W[(k + 2) * FOUT + f], acc);
            acc = fmaf(xv.w, W[(k + 3) * FOUT + f], acc);
        }
        tile[wv * 8 + r8][f] = acc;

        float s1 = acc * af1;
        float s2 = acc * af2;
        #pragma unroll
        for (int off = 32; off; off >>= 1) {
            s1 += __shfl_xor(s1, off, 64);
            s2 += __shfl_xor(s2, off, 64);
        }
        if (f == 0) { Wh1[row] = s1; Wh2[row] = s2; }
    }
    __syncthreads();

    // transpose out: pass p covers f in [p*8, p*8+8), 32 rows each; 2B x 32 lanes
    // contiguous per f (64B). LDS read bank = (r + f) % 32: 2 lanes/bank (free).
    const int r = t & 31;
    const int fh = t >> 5;    // 0..7
    #pragma unroll
    for (int p = 0; p < 8; ++p) {
        const int ff = p * 8 + fh;
        WhT[(size_t)ff * NN + row0 + r] = f2bf(tile[r][ff]);
    }
}

// K2: fused masked softmax numerator/denominator partials via bf16 MFMA.
// grid (NN/BM)*SPLIT = 2048 blocks x 256 threads (4 waves).
// Block (rowblk, slice): rows rowblk*16..+15, j in [slice*2048, +2048).
// Phase A: wave wv computes scores for rows wv*4..+3, thread covers 4 j (int4 adj).
// Phase B: wave wv computes f-tile [16*wv..+15] for all 16 rows via MFMA.
__global__ __launch_bounds__(256) void gat_attn_part(const int* __restrict__ adj,
                                                     const ushort* __restrict__ WhT,
                                                     const float* __restrict__ Wh1,
                                                     const float* __restrict__ Wh2,
                                                     float* __restrict__ pnum,
                                                     float* __restrict__ pden) {
    __shared__ __align__(16) ushort P[2][BM][PROW];   // bf16 score tiles, dbuf

    const int t = threadIdx.x;
    const int lane = t & 63;
    const int wv = t >> 6;
    const int slice = blockIdx.x & (SPLIT - 1);
    const int row0 = (blockIdx.x >> 2) * BM;
    const int j0 = slice * JSLICE;
    const int ln = lane & 15;
    const int quad = lane >> 4;

    const float4 wh1v = *(const float4*)(Wh1 + row0 + wv * 4);   // broadcast
    const int* __restrict__ aptr = adj + (size_t)(row0 + wv * 4) * NN + j0 + lane * 4;

    floatx4 acc = {0.f, 0.f, 0.f, 0.f};
    float den0 = 0.f, den1 = 0.f, den2 = 0.f, den3 = 0.f;

    auto computeP = [&](int c, int b) {
        const int jb = c * CHUNK;
        const float4 wh2v = *(const float4*)(Wh2 + j0 + jb + lane * 4);
        const int4 av0 = *(const int4*)(aptr + (size_t)0 * NN + jb);
        const int4 av1 = *(const int4*)(aptr + (size_t)1 * NN + jb);
        const int4 av2 = *(const int4*)(aptr + (size_t)2 * NN + jb);
        const int4 av3 = *(const int4*)(aptr + (size_t)3 * NN + jb);
#define ROWP(AV, W1, DEN, II)                                              \
        {                                                                  \
            float s0 = (W1) + wh2v.x, s1 = (W1) + wh2v.y,                  \
                  s2 = (W1) + wh2v.z, s3 = (W1) + wh2v.w;                  \
            s0 = fmaxf(s0, ALPHA * s0); s1 = fmaxf(s1, ALPHA * s1);        \
            s2 = fmaxf(s2, ALPHA * s2); s3 = fmaxf(s3, ALPHA * s3);        \
            float p0 = __expf(s0), p1 = __expf(s1),                        \
                  p2 = __expf(s2), p3 = __expf(s3);                        \
            p0 = (AV.x > 0) ? p0 : 0.f; p1 = (AV.y > 0) ? p1 : 0.f;        \
            p2 = (AV.z > 0) ? p2 : 0.f; p3 = (AV.w > 0) ? p3 : 0.f;       \
            DEN += (p0 + p1) + (p2 + p3);                                  \
            ushort4 pk = make_ushort4(f2bf(p0), f2bf(p1), f2bf(p2), f2bf(p3)); \
            *(ushort4*)&P[b][wv * 4 + (II)][lane * 4] = pk;                \
        }
        ROWP(av0, wh1v.x, den0, 0)
        ROWP(av1, wh1v.y, den1, 1)
        ROWP(av2, wh1v.z, den2, 2)
        ROWP(av3, wh1v.w, den3, 3)
#undef ROWP
    };

    computeP(0, 0);
    __syncthreads();

    int pb = 0;
    for (int c = 0; c < NCHUNK; ++c) {
        if (c + 1 < NCHUNK) computeP(c + 1, pb ^ 1);   // adj HBM loads issue early

        const int jb = j0 + c * CHUNK;
        const ushort* Arow = &P[pb][ln][quad * 8];
        const ushort* Brow = WhT + (size_t)(wv * 16 + ln) * NN + jb + quad * 8;
        #pragma unroll
        for (int k0 = 0; k0 < 8; ++k0) {
            short8 afr = *(const short8*)(Arow + k0 * 32);   // ds_read_b128
            short8 bfr = *(const short8*)(Brow + k0 * 32);   // L2-resident 16B
            acc = __builtin_amdgcn_mfma_f32_16x16x32_bf16(afr, bfr, acc, 0, 0, 0);
        }
        __syncthreads();
        pb ^= 1;
    }

    // partial den: wave-64 reduce (wave wv holds partials for rows wv*4..+3)
    float dsum[4] = {den0, den1, den2, den3};
    #pragma unroll
    for (int ii = 0; ii < 4; ++ii) {
        float d = dsum[ii];
        #pragma unroll
        for (int off = 32; off; off >>= 1) d += __shfl_xor(d, off, 64);
        if (lane == 0) pden[(size_t)slice * NN + row0 + wv * 4 + ii] = d;
    }

    // partial num: D[m=quad*4+reg][n=lane&15] (verified C/D layout)
    #pragma unroll
    for (int r = 0; r < 4; ++r) {
        const int i = quad * 4 + r;
        pnum[((size_t)slice * NN + row0 + i) * FOUT + wv * 16 + ln] = acc[r];
    }
}

// K3: combine SPLIT partials, normalize, ELU. grid NN*FOUT/256.
__global__ __launch_bounds__(256) void gat_combine(const float* __restrict__ pnum,
                                                   const float* __restrict__ pden,
                                                   float* __restrict__ out) {
    const int idx = blockIdx.x * 256 + threadIdx.x;
    const int row = idx >> 6;
    float num = 0.f, den = 0.f;
    #pragma unroll
    for (int s = 0; s < SPLIT; ++s) {
        num += pnum[(size_t)s * NN * FOUT + idx];
        den += pden[(size_t)s * NN + row];
    }
    float o = num / den;
    o = (o > 0.f) ? o : (__expf(o) - 1.f);
    out[idx] = o;
}

extern "C" void kernel_launch(void* const* d_in, const int* in_sizes, int n_in,
                              void* d_out, int out_size, void* d_ws, size_t ws_size,
                              hipStream_t stream) {
    const float* x   = (const float*)d_in[0];   // [N, FIN]
    const int*   adj = (const int*)  d_in[1];   // [N, N]
    const float* W   = (const float*)d_in[2];   // [FIN, FOUT]
    const float* a   = (const float*)d_in[3];   // [2*FOUT, 1]
    float* out = (float*)d_out;                 // [N, FOUT]

    // ws: WhT bf16 [64][8192] (1MB) | Wh1 f32 [N] | Wh2 f32 [N]
    //   | pnum f32 [SPLIT][N][FOUT] (8MB) | pden f32 [SPLIT][N] (128KB)
    ushort* WhT = (ushort*)d_ws;
    float* Wh1 = (float*)(WhT + (size_t)FOUT * NN);
    float* Wh2 = Wh1 + NN;
    float* pnum = Wh2 + NN;
    float* pden = pnum + (size_t)SPLIT * NN * FOUT;

    gat_proj<<<NN / 32, 256, 0, stream>>>(x, W, a, WhT, Wh1, Wh2);
    gat_attn_part<<<(NN / BM) * SPLIT, 256, 0, stream>>>(adj, WhT, Wh1, Wh2, pnum, pden);
    gat_combine<<<NN * FOUT / 256, 256, 0, stream>>>(pnum, pden, out);
}